// Round 8
// baseline (1722.995 us; speedup 1.0000x reference)
//
#include <hip/hip_runtime.h>
#include <math.h>

typedef unsigned short u16;
typedef u16 u16x8 __attribute__((ext_vector_type(8)));
typedef u16 u16x4 __attribute__((ext_vector_type(4)));
typedef __bf16 bf16x8 __attribute__((ext_vector_type(8)));
typedef float f32x4 __attribute__((ext_vector_type(4)));

constexpr int NNODE = 23;
constexpr int NB    = 512;
constexpr int NTX   = 28;
constexpr int NTY   = 7;
constexpr int DIN   = 128;
constexpr int DOUT  = 64;
constexpr int DH    = 128;
constexpr int MM    = NNODE * NB;   // 11776 = 512 * 23
constexpr int XW0   = 96;           // padded layer0 x-width
constexpr int K0    = XW0 + DH;     // 224 = 7 k-tiles
constexpr int K1    = DH + DH;      // 256 = 8 k-tiles
constexpr int G4    = 4 * DH;       // 512 gate cols
constexpr int ROWS  = 23;           // rows per block (data-parallel split)
constexpr int RPAD  = 32;           // padded to 2 MFMA m-tiles
constexpr int LDX   = XW0 + 8;      // 104
constexpr int LDH   = DH + 8;       // 136

__device__ __forceinline__ u16 f2bf(float f) {
    unsigned x = __float_as_uint(f);
    return (u16)((x + 0x7fffu + ((x >> 16) & 1u)) >> 16);   // RNE
}
__device__ __forceinline__ float bf2f(u16 u) { return __uint_as_float(((unsigned)u) << 16); }
__device__ __forceinline__ float sigm(float x)  { return __fdividef(1.f, 1.f + __expf(-x)); }
__device__ __forceinline__ float tanh_f(float x){ return __fdividef(2.f, 1.f + __expf(-2.f * x)) - 1.f; }

// ---------------------------------------------------------------------------
// prep: Wt0[512][224] bf16 = [Wih0 | pad | Whh0], Wt1[512][256] bf16,
// b0,b1 f32 = bih+bhh, Wgt[64][128] bf16 = Wg^T (MFMA-B layout for GCN feat).
// ---------------------------------------------------------------------------
__global__ void k_prep(const float* __restrict__ Wih0, const float* __restrict__ Whh0,
                       const float* __restrict__ bih0, const float* __restrict__ bhh0,
                       const float* __restrict__ Wih1, const float* __restrict__ Whh1,
                       const float* __restrict__ bih1, const float* __restrict__ bhh1,
                       const float* __restrict__ Wg,
                       u16* __restrict__ Wt0, u16* __restrict__ Wt1,
                       float* __restrict__ b0, float* __restrict__ b1,
                       u16* __restrict__ Wgt)
{
    int idx = blockIdx.x * blockDim.x + threadIdx.x;
    const int S0 = G4 * K0, S1 = S0 + G4 * K1;
    const int S2 = S1 + 2 * G4;
    if (idx < S0) {
        int c = idx / K0, k = idx - c * K0;
        float val = 0.f;
        if (k < DOUT + 1) val = Wih0[c * (DOUT + 1) + k];
        else if (k >= XW0) val = Whh0[c * DH + (k - XW0)];
        Wt0[idx] = f2bf(val);
    } else if (idx < S1) {
        int i2 = idx - S0;
        int c = i2 / K1, k = i2 - c * K1;
        float val = (k < DH) ? Wih1[c * DH + k] : Whh1[c * DH + (k - DH)];
        Wt1[i2] = f2bf(val);
    } else if (idx < S1 + G4) {
        int j = idx - S1; b0[j] = bih0[j] + bhh0[j];
    } else if (idx < S2) {
        int j = idx - S1 - G4; b1[j] = bih1[j] + bhh1[j];
    } else if (idx < S2 + DOUT * DIN) {
        int i2 = idx - S2;
        int o = i2 / DIN, k = i2 - o * DIN;
        Wgt[i2] = f2bf(Wg[k * DOUT + o]);
    }
}

// infdot[m] = sum_d x_infection[b][d][n] * fc_w[128+d],  m = n*NB + b
__global__ void k_infdot(const float* __restrict__ xinf, const float* __restrict__ fcw,
                         float* __restrict__ idot)
{
    int m = blockIdx.x * blockDim.x + threadIdx.x;
    if (m < MM) {
        int n = m / NB, b = m - n * NB;
        float s = 0.f;
        for (int d = 0; d < NTX; ++d)
            s += xinf[(b * NTX + d) * NNODE + n] * fcw[DH + d];
        idot[m] = s;
    }
}

// ---------------------------------------------------------------------------
// GCN: one block per (b,t), 4 waves. feat = x@Wg via MFMA (bf16 in, f32 acc);
// DAD + relu + scale in f32. seqb rows stride XW0=96, m = n*NB + b.
// ---------------------------------------------------------------------------
__global__ __launch_bounds__(256)
void k_gcn(const float* __restrict__ x, const float* __restrict__ adjs,
           const float* __restrict__ xinf, const float* __restrict__ dayo,
           const float* __restrict__ v, const u16* __restrict__ Wgt,
           u16* __restrict__ seqb)
{
    int bt = blockIdx.x;              // b*NTX + t
    int b = bt / NTX, t = bt - b * NTX;
    __shared__ __align__(16) u16 sXb[32 * LDH];      // x bf16, rows 23..31 zero
    __shared__ float sA[NNODE * NNODE];
    __shared__ float sdinv[NNODE];
    __shared__ float sscale[NNODE];
    __shared__ float sF[NNODE * 68];                 // feat f32, LDF=68
    int tid = threadIdx.x;
    const int w = tid >> 6, lane = tid & 63, lr = lane & 15, kg = lane >> 4;

    // stage x -> bf16 LDS (float4 coalesced)
    const float* x0 = x + (size_t)bt * NNODE * DIN;
    for (int i = tid; i < 32 * 32; i += 256) {
        int r = i >> 5, c4 = i & 31;
        u16x4 pk;
        if (r < NNODE) {
            float4 val = ((const float4*)x0)[r * 32 + c4];
            pk[0] = f2bf(val.x); pk[1] = f2bf(val.y); pk[2] = f2bf(val.z); pk[3] = f2bf(val.w);
        } else { pk[0] = pk[1] = pk[2] = pk[3] = 0; }
        *(u16x4*)(sXb + r * LDH + c4 * 4) = pk;
    }
    const float* adj0 = adjs + (size_t)bt * NNODE * NNODE;
    for (int i = tid; i < NNODE * NNODE; i += 256) {
        int n = i / NNODE, m2 = i - n * NNODE;
        sA[i] = adj0[i] + (n == m2 ? 1.f : 0.f);
    }
    __syncthreads();

    if (tid < NNODE) {
        float s = 0.f;
        for (int m2 = 0; m2 < NNODE; ++m2) s += sA[tid * NNODE + m2];
        sdinv[tid] = rsqrtf(s);
        float vv = v[tid];
        sscale[tid] = __expf(vv * vv * dayo[b]);
    }

    // feat via MFMA: wave w -> cols 16w..16w+15, two 16-row tiles
    {
        const u16* a0 = sXb + lr * LDH + kg * 8;
        const u16* wb = Wgt + (size_t)(16 * w + lr) * DIN + kg * 8;
        f32x4 acc[2];
#pragma unroll
        for (int m = 0; m < 2; ++m)
#pragma unroll
            for (int q = 0; q < 4; ++q) acc[m][q] = 0.f;
#pragma unroll
        for (int kt = 0; kt < 4; ++kt) {
            bf16x8 Bv  = *(const bf16x8*)(wb + kt * 32);
            bf16x8 A0v = *(const bf16x8*)(a0 + kt * 32);
            bf16x8 A1v = *(const bf16x8*)(a0 + 16 * LDH + kt * 32);
            acc[0] = __builtin_amdgcn_mfma_f32_16x16x32_bf16(A0v, Bv, acc[0], 0, 0, 0);
            acc[1] = __builtin_amdgcn_mfma_f32_16x16x32_bf16(A1v, Bv, acc[1], 0, 0, 0);
        }
#pragma unroll
        for (int m = 0; m < 2; ++m)
#pragma unroll
            for (int q = 0; q < 4; ++q) {
                int r = m * 16 + kg * 4 + q;
                if (r < NNODE) sF[r * 68 + 16 * w + lr] = acc[m][q];
            }
    }
    __syncthreads();

    // DAD + relu + scale (f32)
    for (int i = tid; i < NNODE * DOUT; i += 256) {
        int n = i / DOUT, o = i - n * DOUT;
        float acc = 0.f;
        for (int m2 = 0; m2 < NNODE; ++m2)
            acc = fmaf(sA[n * NNODE + m2] * sdinv[m2], sF[m2 * 68 + o], acc);
        acc *= sdinv[n];
        acc = fmaxf(acc, 0.f) * sscale[n];
        seqb[((size_t)t * MM + n * NB + b) * XW0 + o] = f2bf(acc);
    }
    for (int i = tid; i < NNODE * (XW0 - DOUT - 1); i += 256) {
        int n = i / (XW0 - DOUT - 1), o2 = DOUT + 1 + i - n * (XW0 - DOUT - 1);
        seqb[((size_t)t * MM + n * NB + b) * XW0 + o2] = 0;
    }
    if (tid < NNODE)
        seqb[((size_t)t * MM + tid * NB + b) * XW0 + DOUT] = f2bf(xinf[(size_t)bt * NNODE + tid]);
}

// ---------------------------------------------------------------------------
// GEMM helper: 32x512 gate pre-activations, A split across two LDS tiles at
// k-tile SPLIT. 2 m-tiles x 4 gate-tiles per wave; fully unrolled.
// ---------------------------------------------------------------------------
template<int KT, int SPLIT, int LD0, int LD1>
__device__ __forceinline__ void gemm_ab(const u16* A0, const u16* A1,
    const u16* g0, const u16* g1, const u16* g2, const u16* g3,
    f32x4 (&acc)[2][4])
{
#pragma unroll
    for (int m = 0; m < 2; ++m)
#pragma unroll
        for (int g = 0; g < 4; ++g)
#pragma unroll
            for (int q = 0; q < 4; ++q) acc[m][g][q] = 0.f;

#pragma unroll
    for (int kt = 0; kt < KT; ++kt) {
        bf16x8 B0 = *(const bf16x8*)(g0 + kt * 32);
        bf16x8 B1 = *(const bf16x8*)(g1 + kt * 32);
        bf16x8 B2 = *(const bf16x8*)(g2 + kt * 32);
        bf16x8 B3 = *(const bf16x8*)(g3 + kt * 32);
#pragma unroll
        for (int m = 0; m < 2; ++m) {
            bf16x8 Av = *(const bf16x8*)((kt < SPLIT)
                        ? (A0 + m * 16 * LD0 + kt * 32)
                        : (A1 + m * 16 * LD1 + (kt - SPLIT) * 32));
            acc[m][0] = __builtin_amdgcn_mfma_f32_16x16x32_bf16(Av, B0, acc[m][0], 0, 0, 0);
            acc[m][1] = __builtin_amdgcn_mfma_f32_16x16x32_bf16(Av, B1, acc[m][1], 0, 0, 0);
            acc[m][2] = __builtin_amdgcn_mfma_f32_16x16x32_bf16(Av, B2, acc[m][2], 0, 0, 0);
            acc[m][3] = __builtin_amdgcn_mfma_f32_16x16x32_bf16(Av, B3, acc[m][3], 0, 0, 0);
        }
    }
}

__device__ __forceinline__ void epi_plain(const f32x4 (&acc)[2][4], float* cr,
    u16* sHd, float bi, float bf_, float bg, float bo, int kg, int jj)
{
#pragma unroll
    for (int m = 0; m < 2; ++m)
#pragma unroll
        for (int q = 0; q < 4; ++q) {
            int r = m * 16 + kg * 4 + q;
            float gi = acc[m][0][q] + bi, gf = acc[m][1][q] + bf_;
            float gg = acc[m][2][q] + bg, go = acc[m][3][q] + bo;
            float cn = sigm(gf) * cr[m * 4 + q] + sigm(gi) * tanh_f(gg);
            float hn = sigm(go) * tanh_f(cn);
            cr[m * 4 + q] = cn;
            if (r < ROWS) sHd[r * LDH + jj] = f2bf(hn);
        }
}

// ---------------------------------------------------------------------------
// Persistent LSTM scan: 512 blocks x 23 rows x 512 threads (8 waves),
// 2 blocks/CU (LDS 24 KB, VGPR<=128 via launch_bounds(512,4)).
// Smaller per-wave tile (acc[2][4], c 8/layer, xs 8) cuts live VGPRs to ~110
// -> no spill (r5/r6: 1.3-1.5 GB scratch fetch + 170 MB write at VGPR=128).
// Two unsynchronized blocks/CU overlap gemm with epilogue/barriers.
// ---------------------------------------------------------------------------
__global__ __launch_bounds__(512, 4)
void k_scan(const u16* __restrict__ seqb,
            const u16* __restrict__ Wt0, const u16* __restrict__ Wt1,
            const float* __restrict__ b0, const float* __restrict__ b1,
            const float* __restrict__ fcw, const float* __restrict__ idot,
            const float* __restrict__ fcbp, float* __restrict__ out)
{
    __shared__ __align__(16) u16 sX [RPAD * LDX];
    __shared__ __align__(16) u16 sH0[RPAD * LDH];
    __shared__ __align__(16) u16 sH1[RPAD * LDH];
    __shared__ float fcbuf[RPAD];
    const int tid = threadIdx.x, w = tid >> 6, lane = tid & 63;
    const int lr = lane & 15, kg = lane >> 4;
    const int row0 = blockIdx.x * ROWS;
    const int jj = 16 * w + lr;

    // zero h state (pad rows stay zero forever; epilogues write only r<ROWS)
    {
        u16x8 z;
#pragma unroll
        for (int q = 0; q < 8; ++q) z[q] = 0;
        for (int i = tid; i < RPAD * (LDH / 8); i += 512) {
            *(u16x8*)(sH0 + i * 8) = z;
            *(u16x8*)(sH1 + i * 8) = z;
        }
    }

    const float bi0 = b0[jj], bf0 = b0[DH + jj], bg0 = b0[2 * DH + jj], bo0 = b0[3 * DH + jj];
    const float bi1 = b1[jj], bf1 = b1[DH + jj], bg1 = b1[2 * DH + jj], bo1 = b1[3 * DH + jj];
    const float fw  = fcw[jj];
    const float fcb = fcbp[0];
    const float idv = (tid < ROWS) ? idot[row0 + tid] : 0.f;

    const u16* aX  = sX  + lr * LDX + kg * 8;
    const u16* aH0 = sH0 + lr * LDH + kg * 8;
    const u16* aH1 = sH1 + lr * LDH + kg * 8;
    const u16* w00 = Wt0 + (size_t)(0 * DH + jj) * K0 + kg * 8;
    const u16* w01 = Wt0 + (size_t)(1 * DH + jj) * K0 + kg * 8;
    const u16* w02 = Wt0 + (size_t)(2 * DH + jj) * K0 + kg * 8;
    const u16* w03 = Wt0 + (size_t)(3 * DH + jj) * K0 + kg * 8;
    const u16* w10 = Wt1 + (size_t)(0 * DH + jj) * K1 + kg * 8;
    const u16* w11 = Wt1 + (size_t)(1 * DH + jj) * K1 + kg * 8;
    const u16* w12 = Wt1 + (size_t)(2 * DH + jj) * K1 + kg * 8;
    const u16* w13 = Wt1 + (size_t)(3 * DH + jj) * K1 + kg * 8;

    float c0r[8], c1r[8];
#pragma unroll
    for (int i = 0; i < 8; ++i) { c0r[i] = 0.f; c1r[i] = 0.f; }
    float xs[8];
#pragma unroll
    for (int i = 0; i < 8; ++i) xs[i] = 0.f;

    f32x4 acc[2][4];

    // staging map: 32 rows x 12 u16x8-chunks = 384 chunks, tid<384
    const int sr = tid / 12, sck = tid - sr * 12;
    const bool do_stage = (tid < RPAD * 12);
    const bool stage_real = do_stage && (sr < ROWS);

    // ---------------- encoder ----------------
    for (int t = 0; t < NTX; ++t) {
        if (do_stage) {
            u16x8 val;
            if (stage_real) val = *(const u16x8*)(seqb + (size_t)t * MM * XW0 +
                                                 (size_t)(row0 + sr) * XW0 + sck * 8);
            else {
#pragma unroll
                for (int q = 0; q < 8; ++q) val[q] = 0;
            }
            *(u16x8*)(sX + sr * LDX + sck * 8) = val;
#pragma unroll
            for (int q = 0; q < 8; ++q) xs[q] += bf2f(val[q]);
        }
        __syncthreads();
        gemm_ab<7, 3, LDX, LDH>(aX, aH0, w00, w01, w02, w03, acc);
        __syncthreads();
        epi_plain(acc, c0r, sH0, bi0, bf0, bg0, bo0, kg, jj);
        __syncthreads();
        gemm_ab<8, 4, LDH, LDH>(aH0, aH1, w10, w11, w12, w13, acc);
        __syncthreads();
        epi_plain(acc, c1r, sH1, bi1, bf1, bg1, bo1, kg, jj);
        __syncthreads();
    }

    // ---------------- decoder: constant input = mean over encoder days ----
    if (do_stage) {
        u16x8 mv;
#pragma unroll
        for (int q = 0; q < 8; ++q) mv[q] = f2bf(xs[q] * (1.f / NTX));
        *(u16x8*)(sX + sr * LDX + sck * 8) = mv;
    }
    __syncthreads();

    for (int t = 0; t < NTY; ++t) {
        if (tid < RPAD) fcbuf[tid] = 0.f;
        gemm_ab<7, 3, LDX, LDH>(aX, aH0, w00, w01, w02, w03, acc);
        __syncthreads();   // gemm reads done + fcbuf zero visible
        epi_plain(acc, c0r, sH0, bi0, bf0, bg0, bo0, kg, jj);
        __syncthreads();
        gemm_ab<8, 4, LDH, LDH>(aH0, aH1, w10, w11, w12, w13, acc);
        __syncthreads();   // L1 gemm reads of sH1 done
        // L1 epilogue + fused FC
#pragma unroll
        for (int m = 0; m < 2; ++m)
#pragma unroll
            for (int q = 0; q < 4; ++q) {
                int r = m * 16 + kg * 4 + q;
                float gi = acc[m][0][q] + bi1, gf = acc[m][1][q] + bf1;
                float gg = acc[m][2][q] + bg1, go = acc[m][3][q] + bo1;
                float cn = sigm(gf) * c1r[m * 4 + q] + sigm(gi) * tanh_f(gg);
                float hn = sigm(go) * tanh_f(cn);
                c1r[m * 4 + q] = cn;
                if (r < ROWS) sH1[r * LDH + jj] = f2bf(hn);
                float p = hn * fw;
                p += __shfl_xor(p, 1, 64);
                p += __shfl_xor(p, 2, 64);
                p += __shfl_xor(p, 4, 64);
                p += __shfl_xor(p, 8, 64);
                if (lr == 0 && r < ROWS) atomicAdd(&fcbuf[r], p);
            }
        __syncthreads();   // atomics done
        if (tid < ROWS) {
            int gr = row0 + tid;
            int n = gr >> 9, bb = gr & (NB - 1);
            out[((size_t)bb * NTY + t) * NNODE + n] = fmaxf(fcbuf[tid] + idv + fcb, 0.f);
        }
        __syncthreads();
    }
}

// ---------------------------------------------------------------------------
extern "C" void kernel_launch(void* const* d_in, const int* in_sizes, int n_in,
                              void* d_out, int out_size, void* d_ws, size_t ws_size,
                              hipStream_t stream)
{
    const float* x    = (const float*)d_in[0];
    const float* adjs = (const float*)d_in[1];
    const float* xinf = (const float*)d_in[2];
    const float* dayo = (const float*)d_in[3];
    const float* v    = (const float*)d_in[4];
    const float* Wg   = (const float*)d_in[5];
    const float* Wih0 = (const float*)d_in[6];
    const float* Whh0 = (const float*)d_in[7];
    const float* bih0 = (const float*)d_in[8];
    const float* bhh0 = (const float*)d_in[9];
    const float* Wih1 = (const float*)d_in[10];
    const float* Whh1 = (const float*)d_in[11];
    const float* bih1 = (const float*)d_in[12];
    const float* bhh1 = (const float*)d_in[13];
    const float* fcw  = (const float*)d_in[14];
    const float* fcb  = (const float*)d_in[15];
    float* out = (float*)d_out;

    char* p = (char*)d_ws;
    auto alloc = [&](size_t bytes) { void* r = p; p += (bytes + 255) & ~(size_t)255; return r; };
    u16*   seqb = (u16*)alloc((size_t)NTX * MM * XW0 * 2);
    u16*   Wt0  = (u16*)alloc((size_t)G4 * K0 * 2);
    u16*   Wt1  = (u16*)alloc((size_t)G4 * K1 * 2);
    u16*   Wgt  = (u16*)alloc((size_t)DOUT * DIN * 2);
    float* b0   = (float*)alloc(G4 * 4);
    float* b1   = (float*)alloc(G4 * 4);
    float* idot = (float*)alloc(MM * 4);

    const int PREP_TOT = G4 * K0 + G4 * K1 + 2 * G4 + DOUT * DIN;
    k_prep<<<(PREP_TOT + 255) / 256, 256, 0, stream>>>(Wih0, Whh0, bih0, bhh0,
                                                       Wih1, Whh1, bih1, bhh1, Wg,
                                                       Wt0, Wt1, b0, b1, Wgt);
    k_infdot<<<(MM + 255) / 256, 256, 0, stream>>>(xinf, fcw, idot);
    k_gcn<<<NB * NTX, 256, 0, stream>>>(x, adjs, xinf, dayo, v, Wgt, seqb);
    k_scan<<<MM / ROWS, 512, 0, stream>>>(seqb, Wt0, Wt1, b0, b1, fcw, idot, fcb, out);
}

// Round 10
// 1020.039 us; speedup vs baseline: 1.6891x; 1.6891x over previous
//
#include <hip/hip_runtime.h>
#include <math.h>

typedef unsigned short u16;
typedef u16 u16x8 __attribute__((ext_vector_type(8)));
typedef u16 u16x4 __attribute__((ext_vector_type(4)));
typedef __bf16 bf16x8 __attribute__((ext_vector_type(8)));
typedef float f32x4 __attribute__((ext_vector_type(4)));

constexpr int NNODE = 23;
constexpr int NB    = 512;
constexpr int NTX   = 28;
constexpr int NTY   = 7;
constexpr int DIN   = 128;
constexpr int DOUT  = 64;
constexpr int DH    = 128;
constexpr int MM    = NNODE * NB;   // 11776 = 256 * 46
constexpr int XW0   = 96;           // padded layer0 x-width
constexpr int K0    = XW0 + DH;     // 224 = 7 k-tiles
constexpr int K1    = DH + DH;      // 256 = 8 k-tiles
constexpr int G4    = 4 * DH;       // 512 gate cols
constexpr int ROWS  = 46;           // rows per block
constexpr int RPAD  = 48;           // padded to 3 MFMA m-tiles
constexpr int LDX   = XW0 + 8;      // 104
constexpr int LDH   = DH + 8;       // 136

__device__ __forceinline__ u16 f2bf(float f) {
    unsigned x = __float_as_uint(f);
    return (u16)((x + 0x7fffu + ((x >> 16) & 1u)) >> 16);   // RNE
}
__device__ __forceinline__ float bf2f(u16 u) { return __uint_as_float(((unsigned)u) << 16); }
__device__ __forceinline__ float sigm(float x)  { return __fdividef(1.f, 1.f + __expf(-x)); }
__device__ __forceinline__ float tanh_f(float x){ return __fdividef(2.f, 1.f + __expf(-2.f * x)) - 1.f; }

// ---------------------------------------------------------------------------
// prep: Wt0[512][224] bf16 = [Wih0 | pad | Whh0], Wt1[512][256] bf16,
// b0,b1 f32 = bih+bhh, Wgt[64][128] bf16 = Wg^T.
// ---------------------------------------------------------------------------
__global__ void k_prep(const float* __restrict__ Wih0, const float* __restrict__ Whh0,
                       const float* __restrict__ bih0, const float* __restrict__ bhh0,
                       const float* __restrict__ Wih1, const float* __restrict__ Whh1,
                       const float* __restrict__ bih1, const float* __restrict__ bhh1,
                       const float* __restrict__ Wg,
                       u16* __restrict__ Wt0, u16* __restrict__ Wt1,
                       float* __restrict__ b0, float* __restrict__ b1,
                       u16* __restrict__ Wgt)
{
    int idx = blockIdx.x * blockDim.x + threadIdx.x;
    const int S0 = G4 * K0, S1 = S0 + G4 * K1;
    const int S2 = S1 + 2 * G4;
    if (idx < S0) {
        int c = idx / K0, k = idx - c * K0;
        float val = 0.f;
        if (k < DOUT + 1) val = Wih0[c * (DOUT + 1) + k];
        else if (k >= XW0) val = Whh0[c * DH + (k - XW0)];
        Wt0[idx] = f2bf(val);
    } else if (idx < S1) {
        int i2 = idx - S0;
        int c = i2 / K1, k = i2 - c * K1;
        float val = (k < DH) ? Wih1[c * DH + k] : Whh1[c * DH + (k - DH)];
        Wt1[i2] = f2bf(val);
    } else if (idx < S1 + G4) {
        int j = idx - S1; b0[j] = bih0[j] + bhh0[j];
    } else if (idx < S2) {
        int j = idx - S1 - G4; b1[j] = bih1[j] + bhh1[j];
    } else if (idx < S2 + DOUT * DIN) {
        int i2 = idx - S2;
        int o = i2 / DIN, k = i2 - o * DIN;
        Wgt[i2] = f2bf(Wg[k * DOUT + o]);
    }
}

// infdot[m] = sum_d x_infection[b][d][n] * fc_w[128+d],  m = n*NB + b
__global__ void k_infdot(const float* __restrict__ xinf, const float* __restrict__ fcw,
                         float* __restrict__ idot)
{
    int m = blockIdx.x * blockDim.x + threadIdx.x;
    if (m < MM) {
        int n = m / NB, b = m - n * NB;
        float s = 0.f;
        for (int d = 0; d < NTX; ++d)
            s += xinf[(b * NTX + d) * NNODE + n] * fcw[DH + d];
        idot[m] = s;
    }
}

// ---------------------------------------------------------------------------
// GCN: one block per (b,t), 4 waves. feat = x@Wg via MFMA; DAD f32.
// ---------------------------------------------------------------------------
__global__ __launch_bounds__(256)
void k_gcn(const float* __restrict__ x, const float* __restrict__ adjs,
           const float* __restrict__ xinf, const float* __restrict__ dayo,
           const float* __restrict__ v, const u16* __restrict__ Wgt,
           u16* __restrict__ seqb)
{
    int bt = blockIdx.x;              // b*NTX + t
    int b = bt / NTX, t = bt - b * NTX;
    __shared__ __align__(16) u16 sXb[32 * LDH];
    __shared__ float sA[NNODE * NNODE];
    __shared__ float sdinv[NNODE];
    __shared__ float sscale[NNODE];
    __shared__ float sF[NNODE * 68];
    int tid = threadIdx.x;
    const int w = tid >> 6, lane = tid & 63, lr = lane & 15, kg = lane >> 4;

    const float* x0 = x + (size_t)bt * NNODE * DIN;
    for (int i = tid; i < 32 * 32; i += 256) {
        int r = i >> 5, c4 = i & 31;
        u16x4 pk;
        if (r < NNODE) {
            float4 val = ((const float4*)x0)[r * 32 + c4];
            pk[0] = f2bf(val.x); pk[1] = f2bf(val.y); pk[2] = f2bf(val.z); pk[3] = f2bf(val.w);
        } else { pk[0] = pk[1] = pk[2] = pk[3] = 0; }
        *(u16x4*)(sXb + r * LDH + c4 * 4) = pk;
    }
    const float* adj0 = adjs + (size_t)bt * NNODE * NNODE;
    for (int i = tid; i < NNODE * NNODE; i += 256) {
        int n = i / NNODE, m2 = i - n * NNODE;
        sA[i] = adj0[i] + (n == m2 ? 1.f : 0.f);
    }
    __syncthreads();

    if (tid < NNODE) {
        float s = 0.f;
        for (int m2 = 0; m2 < NNODE; ++m2) s += sA[tid * NNODE + m2];
        sdinv[tid] = rsqrtf(s);
        float vv = v[tid];
        sscale[tid] = __expf(vv * vv * dayo[b]);
    }

    {
        const u16* a0 = sXb + lr * LDH + kg * 8;
        const u16* wb = Wgt + (size_t)(16 * w + lr) * DIN + kg * 8;
        f32x4 acc[2];
#pragma unroll
        for (int m = 0; m < 2; ++m)
#pragma unroll
            for (int q = 0; q < 4; ++q) acc[m][q] = 0.f;
#pragma unroll
        for (int kt = 0; kt < 4; ++kt) {
            bf16x8 Bv  = *(const bf16x8*)(wb + kt * 32);
            bf16x8 A0v = *(const bf16x8*)(a0 + kt * 32);
            bf16x8 A1v = *(const bf16x8*)(a0 + 16 * LDH + kt * 32);
            acc[0] = __builtin_amdgcn_mfma_f32_16x16x32_bf16(A0v, Bv, acc[0], 0, 0, 0);
            acc[1] = __builtin_amdgcn_mfma_f32_16x16x32_bf16(A1v, Bv, acc[1], 0, 0, 0);
        }
#pragma unroll
        for (int m = 0; m < 2; ++m)
#pragma unroll
            for (int q = 0; q < 4; ++q) {
                int r = m * 16 + kg * 4 + q;
                if (r < NNODE) sF[r * 68 + 16 * w + lr] = acc[m][q];
            }
    }
    __syncthreads();

    for (int i = tid; i < NNODE * DOUT; i += 256) {
        int n = i / DOUT, o = i - n * DOUT;
        float acc = 0.f;
        for (int m2 = 0; m2 < NNODE; ++m2)
            acc = fmaf(sA[n * NNODE + m2] * sdinv[m2], sF[m2 * 68 + o], acc);
        acc *= sdinv[n];
        acc = fmaxf(acc, 0.f) * sscale[n];
        seqb[((size_t)t * MM + n * NB + b) * XW0 + o] = f2bf(acc);
    }
    for (int i = tid; i < NNODE * (XW0 - DOUT - 1); i += 256) {
        int n = i / (XW0 - DOUT - 1), o2 = DOUT + 1 + i - n * (XW0 - DOUT - 1);
        seqb[((size_t)t * MM + n * NB + b) * XW0 + o2] = 0;
    }
    if (tid < NNODE)
        seqb[((size_t)t * MM + tid * NB + b) * XW0 + DOUT] = f2bf(xinf[(size_t)bt * NNODE + tid]);
}

// ---------------------------------------------------------------------------
// GEMM gate-pair: 2 B-streams live at a time (vs 8 before) -> register demand
// ~130 instead of >256 (r5-r8: spill-bound, 0.6-1.7 GB scratch traffic).
// A re-read from LDS per pair (cheap); sched_barrier(0) after each pair stops
// the scheduler from merging the pairs' load streams back together.
// ---------------------------------------------------------------------------
template<int KT, int SPLIT, int LD0, int LD1>
__device__ __forceinline__ void gemm_pair(const u16* A0, const u16* A1,
    const u16* ga, const u16* gb, f32x4 (&accA)[3], f32x4 (&accB)[3])
{
#pragma unroll
    for (int m = 0; m < 3; ++m)
#pragma unroll
        for (int q = 0; q < 4; ++q) { accA[m][q] = 0.f; accB[m][q] = 0.f; }

#pragma unroll
    for (int kt = 0; kt < KT; ++kt) {
        bf16x8 Ba = *(const bf16x8*)(ga + kt * 32);
        bf16x8 Bb = *(const bf16x8*)(gb + kt * 32);
#pragma unroll
        for (int m = 0; m < 3; ++m) {
            bf16x8 Av = *(const bf16x8*)((kt < SPLIT)
                        ? (A0 + m * 16 * LD0 + kt * 32)
                        : (A1 + m * 16 * LD1 + (kt - SPLIT) * 32));
            accA[m] = __builtin_amdgcn_mfma_f32_16x16x32_bf16(Av, Ba, accA[m], 0, 0, 0);
            accB[m] = __builtin_amdgcn_mfma_f32_16x16x32_bf16(Av, Bb, accB[m], 0, 0, 0);
        }
    }
    __builtin_amdgcn_sched_barrier(0);
}

__device__ __forceinline__ void epi_plain(const f32x4 (&aI)[3], const f32x4 (&aF)[3],
    const f32x4 (&aG)[3], const f32x4 (&aO)[3], float* cr,
    u16* sHd, float bi, float bf_, float bg, float bo, int kg, int jj)
{
#pragma unroll
    for (int m = 0; m < 3; ++m)
#pragma unroll
        for (int q = 0; q < 4; ++q) {
            int r = m * 16 + kg * 4 + q;
            float gi = aI[m][q] + bi, gf = aF[m][q] + bf_;
            float gg = aG[m][q] + bg, go = aO[m][q] + bo;
            float cn = sigm(gf) * cr[m * 4 + q] + sigm(gi) * tanh_f(gg);
            float hn = sigm(go) * tanh_f(cn);
            cr[m * 4 + q] = cn;
            if (r < ROWS) sHd[r * LDH + jj] = f2bf(hn);
        }
}

// ---------------------------------------------------------------------------
// Persistent LSTM scan: 256 blocks x 46 rows x 512 threads (8 waves),
// 1 block/CU. h0/h1 in LDS, c0/c1 in registers; decoder mean in registers.
// launch_bounds(512) only: VGPR cap 256 (2 waves/SIMD), demand ~130 -> fits.
// ---------------------------------------------------------------------------
__global__ __launch_bounds__(512)
void k_scan(const u16* __restrict__ seqb,
            const u16* __restrict__ Wt0, const u16* __restrict__ Wt1,
            const float* __restrict__ b0, const float* __restrict__ b1,
            const float* __restrict__ fcw, const float* __restrict__ idot,
            const float* __restrict__ fcbp, float* __restrict__ out)
{
    __shared__ __align__(16) u16 sX [RPAD * LDX];
    __shared__ __align__(16) u16 sH0[RPAD * LDH];
    __shared__ __align__(16) u16 sH1[RPAD * LDH];
    __shared__ float fcbuf[RPAD];
    const int tid = threadIdx.x, w = tid >> 6, lane = tid & 63;
    const int lr = lane & 15, kg = lane >> 4;
    const int row0 = blockIdx.x * ROWS;
    const int jj = 16 * w + lr;

    {
        u16x8 z;
#pragma unroll
        for (int q = 0; q < 8; ++q) z[q] = 0;
        for (int i = tid; i < RPAD * (LDH / 8); i += 512) {
            *(u16x8*)(sH0 + i * 8) = z;
            *(u16x8*)(sH1 + i * 8) = z;
        }
    }

    const float bi0 = b0[jj], bf0 = b0[DH + jj], bg0 = b0[2 * DH + jj], bo0 = b0[3 * DH + jj];
    const float bi1 = b1[jj], bf1 = b1[DH + jj], bg1 = b1[2 * DH + jj], bo1 = b1[3 * DH + jj];
    const float fw  = fcw[jj];
    const float fcb = fcbp[0];
    const float idv = (tid < ROWS) ? idot[row0 + tid] : 0.f;

    const u16* aX  = sX  + lr * LDX + kg * 8;
    const u16* aH0 = sH0 + lr * LDH + kg * 8;
    const u16* aH1 = sH1 + lr * LDH + kg * 8;
    const u16* w00 = Wt0 + (size_t)(0 * DH + jj) * K0 + kg * 8;
    const u16* w01 = Wt0 + (size_t)(1 * DH + jj) * K0 + kg * 8;
    const u16* w02 = Wt0 + (size_t)(2 * DH + jj) * K0 + kg * 8;
    const u16* w03 = Wt0 + (size_t)(3 * DH + jj) * K0 + kg * 8;
    const u16* w10 = Wt1 + (size_t)(0 * DH + jj) * K1 + kg * 8;
    const u16* w11 = Wt1 + (size_t)(1 * DH + jj) * K1 + kg * 8;
    const u16* w12 = Wt1 + (size_t)(2 * DH + jj) * K1 + kg * 8;
    const u16* w13 = Wt1 + (size_t)(3 * DH + jj) * K1 + kg * 8;

    float c0r[12], c1r[12];
#pragma unroll
    for (int i = 0; i < 12; ++i) { c0r[i] = 0.f; c1r[i] = 0.f; }
    float xs[16];
#pragma unroll
    for (int i = 0; i < 16; ++i) xs[i] = 0.f;

    f32x4 aI[3], aF[3], aG[3], aO[3];

    // ---------------- encoder ----------------
    for (int t = 0; t < NTX; ++t) {
#pragma unroll
        for (int ii = 0; ii < 2; ++ii) {
            int i = tid + ii * 512;
            if (i < 576) {
                int r = i / 12, ck = i - r * 12;
                u16x8 val;
                if (r < ROWS) val = *(const u16x8*)(seqb + (size_t)t * MM * XW0 +
                                                   (size_t)(row0 + r) * XW0 + ck * 8);
                else {
#pragma unroll
                    for (int q = 0; q < 8; ++q) val[q] = 0;
                }
                *(u16x8*)(sX + r * LDX + ck * 8) = val;
#pragma unroll
                for (int q = 0; q < 8; ++q) xs[ii * 8 + q] += bf2f(val[q]);
            }
        }
        __syncthreads();
        gemm_pair<7, 3, LDX, LDH>(aX, aH0, w00, w01, aI, aF);
        gemm_pair<7, 3, LDX, LDH>(aX, aH0, w02, w03, aG, aO);
        __syncthreads();
        epi_plain(aI, aF, aG, aO, c0r, sH0, bi0, bf0, bg0, bo0, kg, jj);
        __syncthreads();
        gemm_pair<8, 4, LDH, LDH>(aH0, aH1, w10, w11, aI, aF);
        gemm_pair<8, 4, LDH, LDH>(aH0, aH1, w12, w13, aG, aO);
        __syncthreads();
        epi_plain(aI, aF, aG, aO, c1r, sH1, bi1, bf1, bg1, bo1, kg, jj);
        __syncthreads();
    }

    // ---------------- decoder: constant input = mean over encoder days ----
#pragma unroll
    for (int ii = 0; ii < 2; ++ii) {
        int i = tid + ii * 512;
        if (i < 576) {
            int r = i / 12, ck = i - r * 12;
            u16x8 mv;
#pragma unroll
            for (int q = 0; q < 8; ++q) mv[q] = f2bf(xs[ii * 8 + q] * (1.f / NTX));
            *(u16x8*)(sX + r * LDX + ck * 8) = mv;
        }
    }
    __syncthreads();

    for (int t = 0; t < NTY; ++t) {
        if (tid < RPAD) fcbuf[tid] = 0.f;
        gemm_pair<7, 3, LDX, LDH>(aX, aH0, w00, w01, aI, aF);
        gemm_pair<7, 3, LDX, LDH>(aX, aH0, w02, w03, aG, aO);
        __syncthreads();
        epi_plain(aI, aF, aG, aO, c0r, sH0, bi0, bf0, bg0, bo0, kg, jj);
        __syncthreads();
        gemm_pair<8, 4, LDH, LDH>(aH0, aH1, w10, w11, aI, aF);
        gemm_pair<8, 4, LDH, LDH>(aH0, aH1, w12, w13, aG, aO);
        __syncthreads();
        // L1 epilogue + fused FC
#pragma unroll
        for (int m = 0; m < 3; ++m)
#pragma unroll
            for (int q = 0; q < 4; ++q) {
                int r = m * 16 + kg * 4 + q;
                float gi = aI[m][q] + bi1, gf = aF[m][q] + bf1;
                float gg = aG[m][q] + bg1, go = aO[m][q] + bo1;
                float cn = sigm(gf) * c1r[m * 4 + q] + sigm(gi) * tanh_f(gg);
                float hn = sigm(go) * tanh_f(cn);
                c1r[m * 4 + q] = cn;
                if (r < ROWS) sH1[r * LDH + jj] = f2bf(hn);
                float p = hn * fw;
                p += __shfl_xor(p, 1, 64);
                p += __shfl_xor(p, 2, 64);
                p += __shfl_xor(p, 4, 64);
                p += __shfl_xor(p, 8, 64);
                if (lr == 0 && r < ROWS) atomicAdd(&fcbuf[r], p);
            }
        __syncthreads();
        if (tid < ROWS) {
            int gr = row0 + tid;
            int n = gr >> 9, bb = gr & (NB - 1);
            out[((size_t)bb * NTY + t) * NNODE + n] = fmaxf(fcbuf[tid] + idv + fcb, 0.f);
        }
        __syncthreads();
    }
}

// ---------------------------------------------------------------------------
extern "C" void kernel_launch(void* const* d_in, const int* in_sizes, int n_in,
                              void* d_out, int out_size, void* d_ws, size_t ws_size,
                              hipStream_t stream)
{
    const float* x    = (const float*)d_in[0];
    const float* adjs = (const float*)d_in[1];
    const float* xinf = (const float*)d_in[2];
    const float* dayo = (const float*)d_in[3];
    const float* v    = (const float*)d_in[4];
    const float* Wg   = (const float*)d_in[5];
    const float* Wih0 = (const float*)d_in[6];
    const float* Whh0 = (const float*)d_in[7];
    const float* bih0 = (const float*)d_in[8];
    const float* bhh0 = (const float*)d_in[9];
    const float* Wih1 = (const float*)d_in[10];
    const float* Whh1 = (const float*)d_in[11];
    const float* bih1 = (const float*)d_in[12];
    const float* bhh1 = (const float*)d_in[13];
    const float* fcw  = (const float*)d_in[14];
    const float* fcb  = (const float*)d_in[15];
    float* out = (float*)d_out;

    char* p = (char*)d_ws;
    auto alloc = [&](size_t bytes) { void* r = p; p += (bytes + 255) & ~(size_t)255; return r; };
    u16*   seqb = (u16*)alloc((size_t)NTX * MM * XW0 * 2);
    u16*   Wt0  = (u16*)alloc((size_t)G4 * K0 * 2);
    u16*   Wt1  = (u16*)alloc((size_t)G4 * K1 * 2);
    u16*   Wgt  = (u16*)alloc((size_t)DOUT * DIN * 2);
    float* b0   = (float*)alloc(G4 * 4);
    float* b1   = (float*)alloc(G4 * 4);
    float* idot = (float*)alloc(MM * 4);

    const int PREP_TOT = G4 * K0 + G4 * K1 + 2 * G4 + DOUT * DIN;
    k_prep<<<(PREP_TOT + 255) / 256, 256, 0, stream>>>(Wih0, Whh0, bih0, bhh0,
                                                       Wih1, Whh1, bih1, bhh1, Wg,
                                                       Wt0, Wt1, b0, b1, Wgt);
    k_infdot<<<(MM + 255) / 256, 256, 0, stream>>>(xinf, fcw, idot);
    k_gcn<<<NB * NTX, 256, 0, stream>>>(x, adjs, xinf, dayo, v, Wgt, seqb);
    k_scan<<<MM / ROWS, 512, 0, stream>>>(seqb, Wt0, Wt1, b0, b1, fcw, idot, fcb, out);
}